// Round 3
// baseline (3701.418 us; speedup 1.0000x reference)
//
#include <hip/hip_runtime.h>
#include <hip/hip_bf16.h>

#define B 4096
#define S 96
#define I_DIM 64
#define HD 128
#define T_STEPS 24
#define N_DIM 64
#define G4 512   // 4*HD
#define BB 8     // batches per LSTM block

__device__ __forceinline__ float sigm(float x) { return 1.0f / (1.0f + expf(-x)); }

__global__ __launch_bounds__(256)
void k_init(const float* __restrict__ h0, const float* __restrict__ c0,
            const float* __restrict__ y0,
            float* __restrict__ h_ws, float* __restrict__ c_ws,
            float* __restrict__ y_ws)
{
    int idx = blockIdx.x * 256 + threadIdx.x;
    if (idx < B * HD) {
        h_ws[idx] = h0[idx];
        c_ws[idx] = c0[idx];
    }
    if (idx < B) y_ws[idx] = y0[idx];
}

// One block per batch element b. 256 threads = 4 waves.
// thread: n = tid&63 (attention node), g = tid>>6 (wave id 0..3)
__global__ __launch_bounds__(256)
void k_attn(const float* __restrict__ H, const float* __restrict__ Wa,
            const float* __restrict__ Ua, const float* __restrict__ ba,
            const float* __restrict__ Va, const float* __restrict__ c_ws,
            float* __restrict__ ctx_ws, int t)
{
    const int b = blockIdx.x, tid = threadIdx.x;
    const int n = tid & 63, g = tid >> 6;

    __shared__ __align__(16) float Hs[S * I_DIM];      // 24 KB
    __shared__ __align__(16) float Was[I_DIM * N_DIM]; // 16 KB
    __shared__ float cs[HD];
    __shared__ float part[4][N_DIM];
    __shared__ float cub[N_DIM];
    __shared__ float lg[S];

    // stage H[b] (6144 f32) via float4 loads
    {
        const float4* src = reinterpret_cast<const float4*>(H + (size_t)b * (S * I_DIM));
        float4* dst = reinterpret_cast<float4*>(Hs);
        for (int k = tid; k < S * I_DIM / 4; k += 256) dst[k] = src[k];
    }
    // stage Wa[:, t, :]: 64 rows x 64 cols; each thread loads 16 contiguous f32
    {
        int f = tid * 16;
        int i = f >> 6, n0 = f & 63;
        const float4* src = reinterpret_cast<const float4*>(Wa + (size_t)i * (T_STEPS * N_DIM) + t * N_DIM + n0);
        float4* dst = reinterpret_cast<float4*>(Was + f);
        dst[0] = src[0];
        dst[1] = src[1];
        dst[2] = src[2];
        dst[3] = src[3];
    }
    if (tid < HD) cs[tid] = c_ws[(size_t)b * HD + tid];
    __syncthreads();

    // cu[n] = sum_hd c[hd] * Ua[hd, t, n]   (split hd over 4 waves)
    {
        float p = 0.0f;
        const float* ua = Ua + (size_t)(g * 32) * (T_STEPS * N_DIM) + t * N_DIM + n;
        #pragma unroll 8
        for (int k = 0; k < 32; ++k)
            p += cs[g * 32 + k] * ua[(size_t)k * (T_STEPS * N_DIM)];
        part[g][n] = p;
    }
    __syncthreads();
    if (tid < N_DIM)
        cub[tid] = part[0][tid] + part[1][tid] + part[2][tid] + part[3][tid]
                 + ba[t * N_DIM + tid];
    __syncthreads();

    // Wa_t column n -> registers
    float wacol[I_DIM];
    #pragma unroll
    for (int i = 0; i < I_DIM; ++i) wacol[i] = Was[i * N_DIM + n];
    const float van = Va[n * T_STEPS + t];
    const float cbn = cub[n];
    const float scale = 0.08838834764831845f; // 1/sqrt(128)

    // logits: wave g handles rows s = g + 4k
    for (int k = 0; k < 24; ++k) {
        int s = g + 4 * k;
        float acc = cbn;
        const float4* hrow = reinterpret_cast<const float4*>(Hs + s * I_DIM);
        #pragma unroll
        for (int i4 = 0; i4 < 16; ++i4) {
            float4 hc = hrow[i4];
            acc += hc.x * wacol[4 * i4]     + hc.y * wacol[4 * i4 + 1]
                 + hc.z * wacol[4 * i4 + 2] + hc.w * wacol[4 * i4 + 3];
        }
        float sc = tanhf(acc) * van;
        #pragma unroll
        for (int off = 32; off; off >>= 1) sc += __shfl_xor(sc, off, 64);
        if (n == 0) lg[s] = sc * scale;
    }
    __syncthreads();

    // softmax over S=96 logits, done by wave 0 (lane l covers s=l and s=64+l)
    if (tid < 64) {
        float v0 = lg[tid];
        float v1 = (tid < 32) ? lg[64 + tid] : -1e30f;
        float m = fmaxf(v0, v1);
        #pragma unroll
        for (int off = 32; off; off >>= 1) m = fmaxf(m, __shfl_xor(m, off, 64));
        float e0 = expf(v0 - m);
        float e1 = (tid < 32) ? expf(v1 - m) : 0.0f;
        float ss = e0 + e1;
        #pragma unroll
        for (int off = 32; off; off >>= 1) ss += __shfl_xor(ss, off, 64);
        float inv = 1.0f / ss;
        lg[tid] = e0 * inv;
        if (tid < 32) lg[64 + tid] = e1 * inv;
    }
    __syncthreads();

    // ctx[i] = sum_s beta[s] * H[s][i]   (split s over 4 waves, i = n)
    {
        float p = 0.0f;
        #pragma unroll 6
        for (int k = 0; k < 24; ++k) {
            int s = g * 24 + k;
            p += lg[s] * Hs[s * I_DIM + n];
        }
        part[g][n] = p;
    }
    __syncthreads();
    if (tid < I_DIM)
        ctx_ws[(size_t)b * I_DIM + tid] =
            part[0][tid] + part[1][tid] + part[2][tid] + part[3][tid];
}

// 8 batches per block, 256 threads. Thread handles gate columns 2*tid, 2*tid+1.
__global__ __launch_bounds__(256)
void k_lstm(const float* __restrict__ W, const float* __restrict__ U,
            const float* __restrict__ bias, const float* __restrict__ fc_w,
            const float* __restrict__ fc_b,
            const float* __restrict__ ctx_ws, float* __restrict__ y_ws,
            float* __restrict__ h_ws, float* __restrict__ c_ws,
            float* __restrict__ out, int t)
{
    const int tid = threadIdx.x;
    const int b0 = blockIdx.x * BB;

    __shared__ float xs[BB][I_DIM];
    __shared__ float hsv[BB][HD];
    __shared__ float yv[BB];
    __shared__ float gates[BB][G4];   // 16 KB

    for (int k = tid; k < BB * I_DIM; k += 256)
        xs[k >> 6][k & 63] = ctx_ws[(size_t)(b0 + (k >> 6)) * I_DIM + (k & 63)];
    for (int k = tid; k < BB * HD; k += 256)
        hsv[k >> 7][k & 127] = h_ws[(size_t)(b0 + (k >> 7)) * HD + (k & 127)];
    if (tid < BB) yv[tid] = y_ws[b0 + tid];
    __syncthreads();

    {
        const int j0 = 2 * tid;
        float a0[BB], a1[BB];
        {
            float2 bw = *reinterpret_cast<const float2*>(&bias[j0]);
            #pragma unroll
            for (int q = 0; q < BB; ++q) { a0[q] = bw.x; a1[q] = bw.y; }
        }
        for (int i = 0; i < I_DIM; ++i) {
            float2 w = *reinterpret_cast<const float2*>(&W[(size_t)i * G4 + j0]);
            #pragma unroll
            for (int q = 0; q < BB; ++q) { float x = xs[q][i]; a0[q] += x * w.x; a1[q] += x * w.y; }
        }
        {
            float2 w = *reinterpret_cast<const float2*>(&W[(size_t)I_DIM * G4 + j0]);
            #pragma unroll
            for (int q = 0; q < BB; ++q) { float x = yv[q]; a0[q] += x * w.x; a1[q] += x * w.y; }
        }
        for (int hd = 0; hd < HD; ++hd) {
            float2 w = *reinterpret_cast<const float2*>(&U[(size_t)hd * G4 + j0]);
            #pragma unroll
            for (int q = 0; q < BB; ++q) { float h = hsv[q][hd]; a0[q] += h * w.x; a1[q] += h * w.y; }
        }
        #pragma unroll
        for (int q = 0; q < BB; ++q) { gates[q][j0] = a0[q]; gates[q][j0 + 1] = a1[q]; }
    }
    __syncthreads();

    // pointwise LSTM update: thread (q = tid>>5, l = tid&31) handles hd = l + 32m
    {
        const int q = tid >> 5, l = tid & 31;
        const int b = b0 + q;
        float ypart = 0.0f;
        #pragma unroll
        for (int m = 0; m < 4; ++m) {
            int hd = l + 32 * m;
            float ig = gates[q][hd];
            float fg = gates[q][HD + hd];
            float gg = gates[q][2 * HD + hd];
            float og = gates[q][3 * HD + hd];
            float cold = c_ws[(size_t)b * HD + hd];
            float cnew = sigm(fg) * cold + sigm(ig) * tanhf(gg);
            float hnew = sigm(og) * tanhf(cnew);
            c_ws[(size_t)b * HD + hd] = cnew;
            h_ws[(size_t)b * HD + hd] = hnew;
            out[(size_t)(B * T_STEPS) + ((size_t)b * T_STEPS + t) * HD + hd] = hnew;
            ypart += hnew * fc_w[t * HD + hd];
        }
        #pragma unroll
        for (int off = 16; off; off >>= 1) ypart += __shfl_xor(ypart, off, 64);
        if (l == 0) {
            float y = ypart + fc_b[t];
            y_ws[b] = y;
            out[(size_t)b * T_STEPS + t] = y;
        }
    }
}

extern "C" void kernel_launch(void* const* d_in, const int* in_sizes, int n_in,
                              void* d_out, int out_size, void* d_ws, size_t ws_size,
                              hipStream_t stream)
{
    const float* H    = (const float*)d_in[0];
    const float* y0   = (const float*)d_in[1];
    const float* h0   = (const float*)d_in[2];
    const float* c0   = (const float*)d_in[3];
    const float* Wa   = (const float*)d_in[4];
    const float* Ua   = (const float*)d_in[5];
    const float* ba   = (const float*)d_in[6];
    const float* Va   = (const float*)d_in[7];
    const float* W    = (const float*)d_in[8];
    const float* U    = (const float*)d_in[9];
    const float* bias = (const float*)d_in[10];
    const float* fc_w = (const float*)d_in[11];
    const float* fc_b = (const float*)d_in[12];
    float* out = (float*)d_out;

    float* ws     = (float*)d_ws;
    float* h_ws   = ws;                    // B*HD
    float* c_ws   = h_ws + (size_t)B * HD; // B*HD
    float* ctx_ws = c_ws + (size_t)B * HD; // B*I
    float* y_ws   = ctx_ws + (size_t)B * I_DIM; // B

    k_init<<<dim3((B * HD + 255) / 256), dim3(256), 0, stream>>>(h0, c0, y0, h_ws, c_ws, y_ws);
    for (int t = 0; t < T_STEPS; ++t) {
        k_attn<<<dim3(B), dim3(256), 0, stream>>>(H, Wa, Ua, ba, Va, c_ws, ctx_ws, t);
        k_lstm<<<dim3(B / BB), dim3(256), 0, stream>>>(W, U, bias, fc_w, fc_b,
                                                       ctx_ws, y_ws, h_ws, c_ws, out, t);
    }
}

// Round 4
// 1468.613 us; speedup vs baseline: 2.5203x; 2.5203x over previous
//
#include <hip/hip_runtime.h>
#include <hip/hip_bf16.h>

#define B 4096
#define S 96
#define I_DIM 64
#define HD 128
#define T_STEPS 24
#define N_DIM 64
#define G4 512   // 4*HD
#define BPB 4    // batches per block (one wave each)
#define HPAD 72  // padded LDS row stride in bf16 elems (2-way bank alias only)

typedef unsigned short u16;
typedef __attribute__((ext_vector_type(8))) short bf16x8;
typedef __attribute__((ext_vector_type(4))) float f32x4;

__device__ __forceinline__ u16 f2b(float f) {
    unsigned int u = __float_as_uint(f);
    unsigned int r = (u + 0x7FFFu + ((u >> 16) & 1u)) >> 16;
    return (u16)r;
}
__device__ __forceinline__ float b2f(u16 x) {
    return __uint_as_float(((unsigned int)x) << 16);
}
__device__ __forceinline__ float sigm(float x) { return 1.0f / (1.0f + expf(-x)); }

__global__ __launch_bounds__(256)
void k_init(const float* __restrict__ h0, const float* __restrict__ c0,
            const float* __restrict__ y0,
            float* __restrict__ h_ws, float* __restrict__ c_ws,
            float* __restrict__ y_ws)
{
    int idx = blockIdx.x * 256 + threadIdx.x;
    if (idx < B * HD) {
        h_ws[idx] = h0[idx];
        c_ws[idx] = c0[idx];
    }
    if (idx < B) y_ws[idx] = y0[idx];
}

// Fused one-step kernel: attention (MFMA score GEMM) + softmax + ctx + LSTM.
// Block = 4 batch elements, 256 threads; wave wv owns batch b0+wv for attention.
__global__ __launch_bounds__(256)
void k_step(const float* __restrict__ H, const float* __restrict__ Wa,
            const float* __restrict__ Ua, const float* __restrict__ ba,
            const float* __restrict__ Va, const float* __restrict__ W,
            const float* __restrict__ U, const float* __restrict__ bias,
            const float* __restrict__ fc_w, const float* __restrict__ fc_b,
            float* __restrict__ y_ws, float* __restrict__ h_ws,
            float* __restrict__ c_ws, float* __restrict__ out, int t)
{
    __shared__ __align__(16) u16 Hs[BPB][S * HPAD];   // 55.3 KB bf16 H tiles
    __shared__ __align__(16) u16 WaT[N_DIM * HPAD];   // 9.2 KB bf16 Wa_t^T [n][i]
    __shared__ float cs[BPB][HD];
    __shared__ float hsv[BPB][HD];
    __shared__ float lg[BPB][S];
    __shared__ float xs[BPB][I_DIM];
    __shared__ float yv[BPB];
    __shared__ float gates[BPB][G4];                  // 8 KB

    const int tid = threadIdx.x;
    const int b0 = blockIdx.x * BPB;
    const int wv = tid >> 6;     // wave id == local batch index
    const int l  = tid & 63;     // lane
    const int b  = b0 + wv;

    // ---- stage H[b] (f32 -> bf16, padded rows), per-wave ----
    {
        const float4* src = reinterpret_cast<const float4*>(H + (size_t)b * (S * I_DIM));
        #pragma unroll
        for (int k2 = 0; k2 < 24; ++k2) {
            int e4 = l + 64 * k2;            // float4 index 0..1535
            float4 v = src[e4];
            int e = e4 * 4;
            int row = e >> 6, col = e & 63;
            ushort4 pk = { f2b(v.x), f2b(v.y), f2b(v.z), f2b(v.w) };
            *reinterpret_cast<ushort4*>(&Hs[wv][row * HPAD + col]) = pk;
        }
    }
    // ---- stage Wa[:,t,:]^T as bf16: WaT[n][i] = Wa[i,t,n] ----
    {
        #pragma unroll
        for (int k = 0; k < 16; ++k) {
            int idx = tid + 256 * k;         // 0..4095
            int i = idx >> 6, n = idx & 63;
            WaT[n * HPAD + i] = f2b(Wa[(size_t)i * (T_STEPS * N_DIM) + t * N_DIM + n]);
        }
    }
    // ---- stage c, h (f32) ----
    #pragma unroll
    for (int k = 0; k < 2; ++k) {
        int idx = tid + 256 * k;             // 0..511
        int q = idx >> 7, d = idx & 127;
        cs[q][d]  = c_ws[(size_t)(b0 + q) * HD + d];
        hsv[q][d] = h_ws[(size_t)(b0 + q) * HD + d];
    }
    if (tid < BPB) yv[tid] = y_ws[b0 + tid];
    __syncthreads();

    // ---- cu[n] = c . Ua[:,t,n] + ba[t,n]  (lane n = l, per-wave batch) ----
    float cbn;
    {
        float p = 0.0f;
        const float* ua = Ua + (size_t)t * N_DIM + l;
        #pragma unroll 32
        for (int hd = 0; hd < HD; ++hd)
            p += cs[wv][hd] * ua[(size_t)hd * (T_STEPS * N_DIM)];
        cbn = p + ba[t * N_DIM + l];
    }
    const float van = Va[l * T_STEPS + t];

    // per-lane copies for the 4 n-tiles (column = nt*16 + (l&15))
    float cbv[4], vav[4];
    #pragma unroll
    for (int nt = 0; nt < 4; ++nt) {
        int n = nt * 16 + (l & 15);
        cbv[nt] = __shfl(cbn, n, 64);
        vav[nt] = __shfl(van, n, 64);
    }

    // ---- B fragments: Wa_t^T, lane holds B[k=(l>>4)*8+j][col=l&15] ----
    bf16x8 bfr[4][2];
    #pragma unroll
    for (int nt = 0; nt < 4; ++nt)
        #pragma unroll
        for (int ks = 0; ks < 2; ++ks) {
            int n = nt * 16 + (l & 15);
            int k = ks * 32 + (l >> 4) * 8;
            bfr[nt][ks] = *reinterpret_cast<const bf16x8*>(&WaT[n * HPAD + k]);
        }

    // ---- score GEMM + tanh epilogue + column-reduce -> logits ----
    const float scale = 0.08838834764831845f; // 1/sqrt(128)
    const u16* hb = Hs[wv];
    for (int mt = 0; mt < 6; ++mt) {
        int row = mt * 16 + (l & 15);
        bf16x8 a0 = *reinterpret_cast<const bf16x8*>(&hb[row * HPAD + (l >> 4) * 8]);
        bf16x8 a1 = *reinterpret_cast<const bf16x8*>(&hb[row * HPAD + 32 + (l >> 4) * 8]);
        float lgp[4] = {0.f, 0.f, 0.f, 0.f};
        #pragma unroll
        for (int nt = 0; nt < 4; ++nt) {
            f32x4 c = {0.f, 0.f, 0.f, 0.f};
            c = __builtin_amdgcn_mfma_f32_16x16x32_bf16(a0, bfr[nt][0], c, 0, 0, 0);
            c = __builtin_amdgcn_mfma_f32_16x16x32_bf16(a1, bfr[nt][1], c, 0, 0, 0);
            #pragma unroll
            for (int i = 0; i < 4; ++i) {
                float sc = c[i] + cbv[nt];
                sc = fminf(fmaxf(sc, -15.f), 15.f);
                float e = __expf(2.0f * sc);
                float th = (e - 1.0f) / (e + 1.0f);
                lgp[i] += th * vav[nt];
            }
        }
        // butterfly sum over the 16-lane column group
        #pragma unroll
        for (int off = 1; off < 16; off <<= 1)
            #pragma unroll
            for (int i = 0; i < 4; ++i) lgp[i] += __shfl_xor(lgp[i], off, 64);
        if ((l & 15) == 0) {
            int g = l >> 4;  // rows g*4..g*4+3 of this M-tile
            #pragma unroll
            for (int i = 0; i < 4; ++i)
                lg[wv][mt * 16 + g * 4 + i] = lgp[i] * scale;
        }
    }

    // ---- per-wave softmax over S=96 ----
    {
        float v0 = lg[wv][l];
        float v1 = (l < 32) ? lg[wv][64 + l] : -1e30f;
        float m = fmaxf(v0, v1);
        #pragma unroll
        for (int off = 32; off; off >>= 1) m = fmaxf(m, __shfl_xor(m, off, 64));
        float e0 = expf(v0 - m);
        float e1 = (l < 32) ? expf(v1 - m) : 0.0f;
        float ss = e0 + e1;
        #pragma unroll
        for (int off = 32; off; off >>= 1) ss += __shfl_xor(ss, off, 64);
        float inv = 1.0f / ss;
        lg[wv][l] = e0 * inv;
        if (l < 32) lg[wv][64 + l] = e1 * inv;
    }

    // ---- ctx[i] = sum_s beta[s] * H[s,i]  (lane i = l) ----
    {
        float ctx = 0.0f;
        #pragma unroll 8
        for (int s = 0; s < S; ++s)
            ctx += lg[wv][s] * b2f(hb[s * HPAD + l]);
        xs[wv][l] = ctx;
    }
    __syncthreads();

    // ---- LSTM gates: thread handles gate cols j0, j0+1 for all 4 batches ----
    {
        const int j0 = 2 * tid;
        float a0[BPB], a1[BPB];
        {
            float2 bw = *reinterpret_cast<const float2*>(&bias[j0]);
            #pragma unroll
            for (int q = 0; q < BPB; ++q) { a0[q] = bw.x; a1[q] = bw.y; }
        }
        for (int i = 0; i < I_DIM; ++i) {
            float2 w = *reinterpret_cast<const float2*>(&W[(size_t)i * G4 + j0]);
            #pragma unroll
            for (int q = 0; q < BPB; ++q) { float x = xs[q][i]; a0[q] += x * w.x; a1[q] += x * w.y; }
        }
        {
            float2 w = *reinterpret_cast<const float2*>(&W[(size_t)I_DIM * G4 + j0]);
            #pragma unroll
            for (int q = 0; q < BPB; ++q) { float x = yv[q]; a0[q] += x * w.x; a1[q] += x * w.y; }
        }
        for (int hd = 0; hd < HD; ++hd) {
            float2 w = *reinterpret_cast<const float2*>(&U[(size_t)hd * G4 + j0]);
            #pragma unroll
            for (int q = 0; q < BPB; ++q) { float h = hsv[q][hd]; a0[q] += h * w.x; a1[q] += h * w.y; }
        }
        #pragma unroll
        for (int q = 0; q < BPB; ++q) { gates[q][j0] = a0[q]; gates[q][j0 + 1] = a1[q]; }
    }
    __syncthreads();

    // ---- pointwise LSTM + y; wave wv handles batch b, lane l -> hd = l, l+64 ----
    {
        float ypart = 0.0f;
        #pragma unroll
        for (int m = 0; m < 2; ++m) {
            int hd = l + 64 * m;
            float ig = gates[wv][hd];
            float fg = gates[wv][HD + hd];
            float gg = gates[wv][2 * HD + hd];
            float og = gates[wv][3 * HD + hd];
            float cold = cs[wv][hd];
            float cnew = sigm(fg) * cold + sigm(ig) * tanhf(gg);
            float hnew = sigm(og) * tanhf(cnew);
            c_ws[(size_t)b * HD + hd] = cnew;
            h_ws[(size_t)b * HD + hd] = hnew;
            out[(size_t)(B * T_STEPS) + ((size_t)b * T_STEPS + t) * HD + hd] = hnew;
            ypart += hnew * fc_w[t * HD + hd];
        }
        #pragma unroll
        for (int off = 32; off; off >>= 1) ypart += __shfl_xor(ypart, off, 64);
        if (l == 0) {
            float y = ypart + fc_b[t];
            y_ws[b] = y;
            out[(size_t)b * T_STEPS + t] = y;
        }
    }
}

extern "C" void kernel_launch(void* const* d_in, const int* in_sizes, int n_in,
                              void* d_out, int out_size, void* d_ws, size_t ws_size,
                              hipStream_t stream)
{
    const float* H    = (const float*)d_in[0];
    const float* y0   = (const float*)d_in[1];
    const float* h0   = (const float*)d_in[2];
    const float* c0   = (const float*)d_in[3];
    const float* Wa   = (const float*)d_in[4];
    const float* Ua   = (const float*)d_in[5];
    const float* ba   = (const float*)d_in[6];
    const float* Va   = (const float*)d_in[7];
    const float* W    = (const float*)d_in[8];
    const float* U    = (const float*)d_in[9];
    const float* bias = (const float*)d_in[10];
    const float* fc_w = (const float*)d_in[11];
    const float* fc_b = (const float*)d_in[12];
    float* out = (float*)d_out;

    float* ws   = (float*)d_ws;
    float* h_ws = ws;                      // B*HD
    float* c_ws = h_ws + (size_t)B * HD;   // B*HD
    float* y_ws = c_ws + (size_t)B * HD;   // B

    k_init<<<dim3((B * HD + 255) / 256), dim3(256), 0, stream>>>(h0, c0, y0, h_ws, c_ws, y_ws);
    for (int t = 0; t < T_STEPS; ++t) {
        k_step<<<dim3(B / BPB), dim3(256), 0, stream>>>(H, Wa, Ua, ba, Va, W, U, bias,
                                                        fc_w, fc_b, y_ws, h_ws, c_ws, out, t);
    }
}

// Round 6
// 1445.025 us; speedup vs baseline: 2.5615x; 1.0163x over previous
//
#include <hip/hip_runtime.h>
#include <hip/hip_bf16.h>

#define B 4096
#define S 96
#define I_DIM 64
#define HD 128
#define T_STEPS 24
#define N_DIM 64
#define G4 512   // 4*HD
#define BPB 4    // batches per block (two waves each)
#define HPAD 72  // padded LDS row stride in bf16 elems

typedef unsigned short u16;
typedef __attribute__((ext_vector_type(8))) short bf16x8;
typedef __attribute__((ext_vector_type(4))) float f32x4;

__device__ __forceinline__ u16 f2b(float f) {
    unsigned int u = __float_as_uint(f);
    unsigned int r = (u + 0x7FFFu + ((u >> 16) & 1u)) >> 16;
    return (u16)r;
}
__device__ __forceinline__ float b2f(u16 x) {
    return __uint_as_float(((unsigned int)x) << 16);
}
__device__ __forceinline__ float sigm(float x) { return 1.0f / (1.0f + expf(-x)); }

__global__ __launch_bounds__(256)
void k_init(const float* __restrict__ h0, const float* __restrict__ c0,
            const float* __restrict__ y0,
            float* __restrict__ h_ws, float* __restrict__ c_ws,
            float* __restrict__ y_ws)
{
    int idx = blockIdx.x * 256 + threadIdx.x;
    if (idx < B * HD) {
        h_ws[idx] = h0[idx];
        c_ws[idx] = c0[idx];
    }
    if (idx < B) y_ws[idx] = y0[idx];
}

// one-time H f32 -> bf16 (linear layout), fully coalesced
__global__ __launch_bounds__(256)
void k_prep(const float* __restrict__ H, u16* __restrict__ Hb)
{
    size_t idx = (size_t)blockIdx.x * 256 + threadIdx.x;   // chunk of 8 elems
    const float4* src = reinterpret_cast<const float4*>(H) + idx * 2;
    float4 v0 = src[0], v1 = src[1];
    ushort4 p0 = { f2b(v0.x), f2b(v0.y), f2b(v0.z), f2b(v0.w) };
    ushort4 p1 = { f2b(v1.x), f2b(v1.y), f2b(v1.z), f2b(v1.w) };
    ushort4* dst = reinterpret_cast<ushort4*>(Hb + idx * 8);
    dst[0] = p0;
    dst[1] = p1;
}

// Fused step: 512 threads, 4 batches/block, 2 waves per batch.
template<bool PRE>
__global__ __launch_bounds__(512)
void k_step(const float* __restrict__ H, const u16* __restrict__ Hb,
            const float* __restrict__ Wa, const float* __restrict__ Ua,
            const float* __restrict__ ba, const float* __restrict__ Va,
            const float* __restrict__ W, const float* __restrict__ U,
            const float* __restrict__ bias, const float* __restrict__ fc_w,
            const float* __restrict__ fc_b,
            float* __restrict__ y_ws, float* __restrict__ h_ws,
            float* __restrict__ c_ws, float* __restrict__ out, int t)
{
    __shared__ __align__(16) u16 Hs[BPB][S * HPAD];   // 55.3 KB
    __shared__ __align__(16) u16 WaT[N_DIM * HPAD];   // 9.2 KB
    __shared__ float cs[BPB][HD];
    __shared__ float hsv[BPB][HD];
    __shared__ float lg[BPB][S];
    __shared__ float xs2[2][BPB][I_DIM];
    __shared__ float yv[BPB];
    __shared__ float gates[BPB][G4];                  // 8 KB
    __shared__ float ypb[8];

    const int tid = threadIdx.x;
    const int wv = tid >> 6, l = tid & 63;
    const int q = wv >> 1, half = wv & 1;   // batch slot, M-half
    const int b0 = blockIdx.x * BPB, b = b0 + q;
    const int u = half * 64 + l;            // 0..127 within batch's thread group

    // ---- stage H[b] into padded LDS rows ----
    if (PRE) {
        const int4* src = reinterpret_cast<const int4*>(Hb + (size_t)b * (S * I_DIM));
        #pragma unroll
        for (int k = 0; k < 6; ++k) {
            int e8 = u + 128 * k;           // ushort8 chunk 0..767
            int4 v = src[e8];
            int row = e8 >> 3, col = (e8 & 7) * 8;
            *reinterpret_cast<int4*>(&Hs[q][row * HPAD + col]) = v;
        }
    } else {
        const float4* src = reinterpret_cast<const float4*>(H + (size_t)b * (S * I_DIM));
        #pragma unroll
        for (int k = 0; k < 12; ++k) {
            int e4 = u + 128 * k;           // float4 chunk 0..1535
            float4 v = src[e4];
            int e = e4 * 4;
            int row = e >> 6, col = e & 63;
            ushort4 pk = { f2b(v.x), f2b(v.y), f2b(v.z), f2b(v.w) };
            *reinterpret_cast<ushort4*>(&Hs[q][row * HPAD + col]) = pk;
        }
    }
    // ---- stage Wa[:,t,:]^T bf16 ----
    #pragma unroll
    for (int k = 0; k < 8; ++k) {
        int idx = tid + 512 * k;            // 0..4095
        int i = idx >> 6, n = idx & 63;
        WaT[n * HPAD + i] = f2b(Wa[(size_t)i * (T_STEPS * N_DIM) + t * N_DIM + n]);
    }
    // ---- stage c, h ----
    {
        int q2 = tid >> 7, d = tid & 127;
        cs[q2][d]  = c_ws[(size_t)(b0 + q2) * HD + d];
        hsv[q2][d] = h_ws[(size_t)(b0 + q2) * HD + d];
    }
    if (tid < BPB) yv[tid] = y_ws[b0 + tid];
    __syncthreads();

    // ---- cu[n] = c . Ua[:,t,n] + ba[t,n]  (redundant per wave-pair) ----
    float cbn;
    {
        float p = 0.0f;
        const float* ua = Ua + (size_t)t * N_DIM + l;
        #pragma unroll 16
        for (int hd = 0; hd < HD; ++hd)
            p += cs[q][hd] * ua[(size_t)hd * (T_STEPS * N_DIM)];
        cbn = p + ba[t * N_DIM + l];
    }
    const float van = Va[l * T_STEPS + t];
    float cbv[4], vav[4];
    #pragma unroll
    for (int nt = 0; nt < 4; ++nt) {
        int n = nt * 16 + (l & 15);
        cbv[nt] = __shfl(cbn, n, 64);
        vav[nt] = __shfl(van, n, 64);
    }

    // ---- B fragments ----
    bf16x8 bfr[4][2];
    #pragma unroll
    for (int nt = 0; nt < 4; ++nt)
        #pragma unroll
        for (int ks = 0; ks < 2; ++ks) {
            int n = nt * 16 + (l & 15);
            int k = ks * 32 + (l >> 4) * 8;
            bfr[nt][ks] = *reinterpret_cast<const bf16x8*>(&WaT[n * HPAD + k]);
        }

    // ---- score GEMM + tanh + column-reduce: wave handles 3 of 6 M-tiles ----
    const float scale = 0.08838834764831845f; // 1/sqrt(128)
    const u16* hb = Hs[q];
    for (int mt = 0; mt < 3; ++mt) {
        int mtile = half * 3 + mt;
        int row = mtile * 16 + (l & 15);
        bf16x8 a0 = *reinterpret_cast<const bf16x8*>(&hb[row * HPAD + (l >> 4) * 8]);
        bf16x8 a1 = *reinterpret_cast<const bf16x8*>(&hb[row * HPAD + 32 + (l >> 4) * 8]);
        float lgp[4] = {0.f, 0.f, 0.f, 0.f};
        #pragma unroll
        for (int nt = 0; nt < 4; ++nt) {
            f32x4 c = {0.f, 0.f, 0.f, 0.f};
            c = __builtin_amdgcn_mfma_f32_16x16x32_bf16(a0, bfr[nt][0], c, 0, 0, 0);
            c = __builtin_amdgcn_mfma_f32_16x16x32_bf16(a1, bfr[nt][1], c, 0, 0, 0);
            #pragma unroll
            for (int i = 0; i < 4; ++i) {
                float sc = c[i] + cbv[nt];
                sc = fminf(fmaxf(sc, -15.f), 15.f);
                float e = __expf(2.0f * sc);
                float th = (e - 1.0f) / (e + 1.0f);
                lgp[i] += th * vav[nt];
            }
        }
        #pragma unroll
        for (int off = 1; off < 16; off <<= 1)
            #pragma unroll
            for (int i = 0; i < 4; ++i) lgp[i] += __shfl_xor(lgp[i], off, 64);
        if ((l & 15) == 0) {
            int g = l >> 4;
            #pragma unroll
            for (int i = 0; i < 4; ++i)
                lg[q][mtile * 16 + g * 4 + i] = lgp[i] * scale;
        }
    }
    __syncthreads();

    // ---- softmax (redundant per wave); read-all then write-halves ----
    float beta0, beta1;
    {
        float v0 = lg[q][l];
        float v1 = (l < 32) ? lg[q][64 + l] : -1e30f;
        float m = fmaxf(v0, v1);
        #pragma unroll
        for (int off = 32; off; off >>= 1) m = fmaxf(m, __shfl_xor(m, off, 64));
        float e0 = expf(v0 - m);
        float e1 = (l < 32) ? expf(v1 - m) : 0.0f;
        float ss = e0 + e1;
        #pragma unroll
        for (int off = 32; off; off >>= 1) ss += __shfl_xor(ss, off, 64);
        float inv = 1.0f / ss;
        beta0 = e0 * inv;
        beta1 = e1 * inv;
    }
    __syncthreads();
    if (half == 0) lg[q][l] = beta0;
    else if (l < 32) lg[q][64 + l] = beta1;
    __syncthreads();

    // ---- ctx partial: wave sums its 48 s-rows, lane = i ----
    {
        float p = 0.0f;
        #pragma unroll 8
        for (int k = 0; k < 48; ++k) {
            int s = half * 48 + k;
            p += lg[q][s] * b2f(hb[s * HPAD + l]);
        }
        xs2[half][q][l] = p;
    }
    __syncthreads();

    // ---- LSTM gates: thread owns gate column j = tid for all 4 batches ----
    {
        const int j = tid;
        float a[BPB];
        float bj = bias[j];
        #pragma unroll
        for (int qq = 0; qq < BPB; ++qq) a[qq] = bj;
        for (int i = 0; i < I_DIM; ++i) {
            float w = W[(size_t)i * G4 + j];
            #pragma unroll
            for (int qq = 0; qq < BPB; ++qq) {
                float x = xs2[0][qq][i] + xs2[1][qq][i];
                a[qq] += x * w;
            }
        }
        {
            float w = W[(size_t)I_DIM * G4 + j];
            #pragma unroll
            for (int qq = 0; qq < BPB; ++qq) a[qq] += yv[qq] * w;
        }
        for (int hd = 0; hd < HD; ++hd) {
            float w = U[(size_t)hd * G4 + j];
            #pragma unroll
            for (int qq = 0; qq < BPB; ++qq) a[qq] += hsv[qq][hd] * w;
        }
        #pragma unroll
        for (int qq = 0; qq < BPB; ++qq) gates[qq][j] = a[qq];
    }
    __syncthreads();

    // ---- pointwise LSTM + y: wave pair per batch, lane -> hd = l + 64*half ----
    {
        int hd = l + 64 * half;
        float ig = gates[q][hd];
        float fg = gates[q][HD + hd];
        float gg = gates[q][2 * HD + hd];
        float og = gates[q][3 * HD + hd];
        float cold = cs[q][hd];
        float cnew = sigm(fg) * cold + sigm(ig) * tanhf(gg);
        float hnew = sigm(og) * tanhf(cnew);
        c_ws[(size_t)b * HD + hd] = cnew;
        h_ws[(size_t)b * HD + hd] = hnew;
        out[(size_t)(B * T_STEPS) + ((size_t)b * T_STEPS + t) * HD + hd] = hnew;
        float yp = hnew * fc_w[t * HD + hd];
        #pragma unroll
        for (int off = 32; off; off >>= 1) yp += __shfl_xor(yp, off, 64);
        if (l == 0) ypb[wv] = yp;
    }
    __syncthreads();
    if (tid < BPB) {
        float y = ypb[2 * tid] + ypb[2 * tid + 1] + fc_b[t];
        y_ws[b0 + tid] = y;
        out[(size_t)(b0 + tid) * T_STEPS + t] = y;
    }
}

extern "C" void kernel_launch(void* const* d_in, const int* in_sizes, int n_in,
                              void* d_out, int out_size, void* d_ws, size_t ws_size,
                              hipStream_t stream)
{
    const float* H    = (const float*)d_in[0];
    const float* y0   = (const float*)d_in[1];
    const float* h0   = (const float*)d_in[2];
    const float* c0   = (const float*)d_in[3];
    const float* Wa   = (const float*)d_in[4];
    const float* Ua   = (const float*)d_in[5];
    const float* ba   = (const float*)d_in[6];
    const float* Va   = (const float*)d_in[7];
    const float* W    = (const float*)d_in[8];
    const float* U    = (const float*)d_in[9];
    const float* bias = (const float*)d_in[10];
    const float* fc_w = (const float*)d_in[11];
    const float* fc_b = (const float*)d_in[12];
    float* out = (float*)d_out;

    float* ws   = (float*)d_ws;
    float* h_ws = ws;                      // B*HD
    float* c_ws = h_ws + (size_t)B * HD;   // B*HD
    float* y_ws = c_ws + (size_t)B * HD;   // B
    u16*   Hb   = (u16*)(y_ws + B);        // B*S*I bf16

    size_t need = ((size_t)2 * B * HD + B) * sizeof(float)
                + (size_t)B * S * I_DIM * sizeof(u16);
    bool pre = ws_size >= need;

    k_init<<<dim3((B * HD + 255) / 256), dim3(256), 0, stream>>>(h0, c0, y0, h_ws, c_ws, y_ws);
    if (pre)
        k_prep<<<dim3(B * S * I_DIM / 8 / 256), dim3(256), 0, stream>>>(H, Hb);

    for (int t = 0; t < T_STEPS; ++t) {
        if (pre)
            k_step<true><<<dim3(B / BPB), dim3(512), 0, stream>>>(H, Hb, Wa, Ua, ba, Va, W, U,
                bias, fc_w, fc_b, y_ws, h_ws, c_ws, out, t);
        else
            k_step<false><<<dim3(B / BPB), dim3(512), 0, stream>>>(H, Hb, Wa, Ua, ba, Va, W, U,
                bias, fc_w, fc_b, y_ws, h_ws, c_ws, out, t);
    }
}